// Round 4
// baseline (1745.411 us; speedup 1.0000x reference)
//
#include <hip/hip_runtime.h>
#include <hip/hip_bf16.h>

#define NN 100000
#define EE 1250000
#define DD 64
#define GG 256
#define BN_NODES 16
#define NBUCK (NN / BN_NODES)   // 6250 (exact)

static __device__ __forceinline__ float relu_f(float x) { return fmaxf(x, 0.0f); }

static __device__ __forceinline__ float b2f(ushort u) {
    return __uint_as_float(((unsigned int)u) << 16);
}
static __device__ __forceinline__ ushort f2b(float f) {
    __hip_bfloat16 h = __float2bfloat16(f);  // RNE
    return *(ushort*)&h;
}

// ---------------- coarse bucket sort of edges by dst>>4 ----------------

__global__ void bhist_kernel(const int* __restrict__ dst, int* __restrict__ bhist, int E) {
    int e = blockIdx.x * blockDim.x + threadIdx.x;
    if (e < E) atomicAdd(&bhist[dst[e] >> 4], 1);
}

// single-block exclusive scan over NBUCK=6250 (7 chunks of 1024)
__global__ __launch_bounds__(1024) void bscan_kernel(
    const int* __restrict__ bhist, int* __restrict__ boffs, int* __restrict__ bcursor) {
    __shared__ int tmp[1024];
    __shared__ int carry;
    int t = threadIdx.x;
    if (t == 0) carry = 0;
    __syncthreads();
    for (int base = 0; base < NBUCK; base += 1024) {
        int v = (base + t < NBUCK) ? bhist[base + t] : 0;
        tmp[t] = v;
        __syncthreads();
        for (int d = 1; d < 1024; d <<= 1) {
            int u = (t >= d) ? tmp[t - d] : 0;
            __syncthreads();
            tmp[t] += u;
            __syncthreads();
        }
        int excl = tmp[t] - v + carry;   // reads carry from previous chunks
        if (base + t < NBUCK) { boffs[base + t] = excl; bcursor[base + t] = excl; }
        __syncthreads();
        if (t == 1023) carry += tmp[1023];
        __syncthreads();
    }
    if (t == 0) boffs[NBUCK] = carry;
}

// pack src (17 bits) | dstLocal (4 bits) << 20 into one int, bucket-grouped
__global__ void bscatter_kernel(const int* __restrict__ ei, int* __restrict__ bcursor,
                                int* __restrict__ epack, int E) {
    int e = blockIdx.x * blockDim.x + threadIdx.x;
    if (e < E) {
        int s = ei[e];          // src
        int d = ei[E + e];      // dst
        int pos = atomicAdd(&bcursor[d >> 4], 1);
        epack[pos] = s | ((d & (BN_NODES - 1)) << 20);
    }
}

// graph boundaries from sorted batch
__global__ void bounds_kernel(const int* __restrict__ batch, int* __restrict__ gstart, int n) {
    int i = blockIdx.x * blockDim.x + threadIdx.x;
    if (i >= n) return;
    int b = batch[i];
    int prev = (i == 0) ? -1 : batch[i - 1];
    for (int g = prev + 1; g <= b; g++) gstart[g] = i;
    if (i == n - 1) {
        for (int g = b + 1; g <= GG; g++) gstart[g] = n;
    }
}

// fp32 -> bf16 cast of x (once)
__global__ __launch_bounds__(256) void cast_kernel(const float* __restrict__ x,
                                                   ushort* __restrict__ xb) {
    size_t i = ((size_t)blockIdx.x * blockDim.x + threadIdx.x) * 4;
    if (i >= (size_t)NN * DD) return;
    float4 v = *(const float4*)(x + i);
    ushort4 r;
    r.x = f2b(v.x); r.y = f2b(v.y); r.z = f2b(v.z); r.w = f2b(v.w);
    *(ushort4*)(xb + i) = r;
}

// ---------------- aggregation: wave per 16-node bucket, LDS accumulate -----
// u[i] = x[i] + sum_{j in-neighbors} x[src_j]   (fp32 accumulate, fp32 out)
__global__ __launch_bounds__(256) void aggB_kernel(
    const ushort* __restrict__ xb, float* __restrict__ u,
    const int* __restrict__ boffs, const int* __restrict__ epack) {
    __shared__ float accum[4][BN_NODES * DD];   // 4 waves x 4KB = 16KB
    int wave = threadIdx.x >> 6, lane = threadIdx.x & 63;
    int b = blockIdx.x * 4 + wave;
    if (b >= NBUCK) return;                     // no barriers below -> safe
    float* acc = accum[wave];
#pragma unroll
    for (int r = 0; r < BN_NODES; r++) acc[r * DD + lane] = 0.0f;
    int j = boffs[b], je = boffs[b + 1];
    for (; j + 4 <= je; j += 4) {
        int p0 = epack[j + 0], p1 = epack[j + 1], p2 = epack[j + 2], p3 = epack[j + 3];
        ushort v0 = xb[(size_t)(p0 & 0xFFFFF) * DD + lane];   // 4 gathers in flight
        ushort v1 = xb[(size_t)(p1 & 0xFFFFF) * DD + lane];
        ushort v2 = xb[(size_t)(p2 & 0xFFFFF) * DD + lane];
        ushort v3 = xb[(size_t)(p3 & 0xFFFFF) * DD + lane];
        atomicAdd(&acc[(p0 >> 20) * DD + lane], b2f(v0));     // ds_add_f32, no ret dep
        atomicAdd(&acc[(p1 >> 20) * DD + lane], b2f(v1));
        atomicAdd(&acc[(p2 >> 20) * DD + lane], b2f(v2));
        atomicAdd(&acc[(p3 >> 20) * DD + lane], b2f(v3));
    }
    for (; j < je; j++) {
        int p = epack[j];
        atomicAdd(&acc[(p >> 20) * DD + lane], b2f(xb[(size_t)(p & 0xFFFFF) * DD + lane]));
    }
    int nbase = b * BN_NODES;
#pragma unroll
    for (int r = 0; r < BN_NODES; r++) {
        float s = b2f(xb[(size_t)(nbase + r) * DD + lane]);   // self term
        u[(size_t)(nbase + r) * DD + lane] = acc[r * DD + lane] + s;
    }
}

// ---------------- per-layer: fused MLP + outer ReLU (+ BN) -----------------
template <bool HAS_BN, bool OUT_BF16>
__global__ __launch_bounds__(256) void mlp_kernel(
    const float* __restrict__ u, void* __restrict__ hout,
    const float* __restrict__ wa, const float* __restrict__ ba,
    const float* __restrict__ wb, const float* __restrict__ bb,
    const float* __restrict__ bng, const float* __restrict__ bnb,
    const float* __restrict__ bnm, const float* __restrict__ bnv, int n) {
    int i = blockIdx.x * blockDim.x + threadIdx.x;
    if (i >= n) return;

    float uu[DD];
    const float4* up = (const float4*)(u + (size_t)i * DD);
#pragma unroll
    for (int q = 0; q < DD / 4; q++) {
        float4 v = up[q];
        uu[4 * q + 0] = v.x; uu[4 * q + 1] = v.y;
        uu[4 * q + 2] = v.z; uu[4 * q + 3] = v.w;
    }

    float acc[DD];
#pragma unroll
    for (int o = 0; o < DD; o++) acc[o] = bb[o];

#pragma unroll 1
    for (int j = 0; j < DD; j++) {   // j wave-uniform -> weight loads go scalar
        float a = ba[j];
#pragma unroll
        for (int k = 0; k < DD; k++) a = fmaf(uu[k], wa[k * DD + j], a);
        a = relu_f(a);
#pragma unroll
        for (int o = 0; o < DD; o++) acc[o] = fmaf(a, wb[j * DD + o], acc[o]);
    }

#pragma unroll
    for (int q = 0; q < DD / 4; q++) {
        float v[4];
#pragma unroll
        for (int c = 0; c < 4; c++) {
            int o = 4 * q + c;
            float t = relu_f(acc[o]);
            if (HAS_BN) {
                float sc = bng[o] * rsqrtf(bnv[o] + 1e-5f);
                float sh = bnb[o] - bnm[o] * sc;
                t = fmaf(t, sc, sh);
            }
            v[c] = t;
        }
        if (OUT_BF16) {
            ushort4 r;
            r.x = f2b(v[0]); r.y = f2b(v[1]); r.z = f2b(v[2]); r.w = f2b(v[3]);
            ((ushort4*)((ushort*)hout + (size_t)i * DD))[q] = r;
        } else {
            float4 r; r.x = v[0]; r.y = v[1]; r.z = v[2]; r.w = v[3];
            ((float4*)((float*)hout + (size_t)i * DD))[q] = r;
        }
    }
}

// ---------------- pooling: one block per graph, zero atomics ----------------
__global__ __launch_bounds__(256) void pool_kernel(
    const float* __restrict__ h, const int* __restrict__ gstart,
    float* __restrict__ pmean, float* __restrict__ pmax) {
    __shared__ float ssum[4][DD];
    __shared__ float smax[4][DD];
    int g = blockIdx.x;
    int lane = threadIdx.x & 63;
    int wave = threadIdx.x >> 6;
    int s = gstart[g], e = gstart[g + 1];
    float sum = 0.0f, mx = 0.0f;  // layer-2 out is post-ReLU >= 0; 0 == empty-graph guard
    for (int i = s + wave; i < e; i += 4) {
        float v = h[(size_t)i * DD + lane];
        sum += v;
        mx = fmaxf(mx, v);
    }
    ssum[wave][lane] = sum;
    smax[wave][lane] = mx;
    __syncthreads();
    if (wave == 0) {
        sum = ssum[0][lane] + ssum[1][lane] + ssum[2][lane] + ssum[3][lane];
        mx = fmaxf(fmaxf(smax[0][lane], smax[1][lane]),
                   fmaxf(smax[2][lane], smax[3][lane]));
        float cnt = fmaxf((float)(e - s), 1.0f);
        pmean[g * DD + lane] = sum / cnt;
        pmax[g * DD + lane] = mx;
    }
}

// ---------------- head: MLP + log_softmax, one 64-thread block per graph ----
__global__ __launch_bounds__(64) void head_kernel(
    const float* __restrict__ pmean, const float* __restrict__ pmax,
    const float* __restrict__ wp1, const float* __restrict__ bp1,
    const float* __restrict__ wp2, const float* __restrict__ bp2,
    float* __restrict__ out) {
    __shared__ float gx[2 * DD];
    int g = blockIdx.x;
    int lane = threadIdx.x;
    gx[lane] = pmean[g * DD + lane];
    gx[DD + lane] = pmax[g * DD + lane];
    __syncthreads();
    float t = bp1[lane];
    for (int k = 0; k < 2 * DD; k++) t = fmaf(gx[k], wp1[k * DD + lane], t);
    float p0 = t * wp2[lane * 2 + 0];
    float p1 = t * wp2[lane * 2 + 1];
    for (int o = 32; o > 0; o >>= 1) {
        p0 += __shfl_down(p0, o);
        p1 += __shfl_down(p1, o);
    }
    if (lane == 0) {
        p0 += bp2[0];
        p1 += bp2[1];
        float m = fmaxf(p0, p1);
        float lse = m + logf(expf(p0 - m) + expf(p1 - m));
        out[g * 2 + 0] = p0 - lse;
        out[g * 2 + 1] = p1 - lse;
    }
}

// ---------------- launch ----------------
extern "C" void kernel_launch(void* const* d_in, const int* in_sizes, int n_in,
                              void* d_out, int out_size, void* d_ws, size_t ws_size,
                              hipStream_t stream) {
    const float* x     = (const float*)d_in[0];
    const int*   ei    = (const int*)d_in[1];
    const int*   batch = (const int*)d_in[2];
    const float* w0a = (const float*)d_in[3];  const float* b0a = (const float*)d_in[4];
    const float* w0b = (const float*)d_in[5];  const float* b0b = (const float*)d_in[6];
    const float* w1a = (const float*)d_in[7];  const float* b1a = (const float*)d_in[8];
    const float* w1b = (const float*)d_in[9];  const float* b1b = (const float*)d_in[10];
    const float* w2a = (const float*)d_in[11]; const float* b2a = (const float*)d_in[12];
    const float* w2b = (const float*)d_in[13]; const float* b2b = (const float*)d_in[14];
    const float* bn0g = (const float*)d_in[15]; const float* bn0b = (const float*)d_in[16];
    const float* bn0m = (const float*)d_in[17]; const float* bn0v = (const float*)d_in[18];
    const float* bn1g = (const float*)d_in[19]; const float* bn1b = (const float*)d_in[20];
    const float* bn1m = (const float*)d_in[21]; const float* bn1v = (const float*)d_in[22];
    const float* wp1 = (const float*)d_in[23]; const float* bp1 = (const float*)d_in[24];
    const float* wp2 = (const float*)d_in[25]; const float* bp2 = (const float*)d_in[26];
    float* out = (float*)d_out;

    char* p = (char*)d_ws;
    auto take = [&](size_t bytes) {
        char* r = p;
        p += (bytes + 255) & ~(size_t)255;
        return r;
    };
    int* bhist   = (int*)take(NBUCK * sizeof(int));
    int* boffs   = (int*)take((NBUCK + 1) * sizeof(int));
    int* bcursor = (int*)take(NBUCK * sizeof(int));
    int* epack   = (int*)take(EE * sizeof(int));
    int* gstart  = (int*)take((GG + 1) * sizeof(int));
    ushort* xb   = (ushort*)take((size_t)NN * DD * sizeof(ushort));
    float* bufU  = (float*)take((size_t)NN * DD * sizeof(float));
    ushort* hA   = (ushort*)take((size_t)NN * DD * sizeof(ushort));
    ushort* hB   = (ushort*)take((size_t)NN * DD * sizeof(ushort));
    float* pmean = (float*)take(GG * DD * sizeof(float));
    float* pmax  = (float*)take(GG * DD * sizeof(float));

    // bucket sort + graph bounds + x cast
    hipMemsetAsync(bhist, 0, NBUCK * sizeof(int), stream);
    bhist_kernel<<<(EE + 255) / 256, 256, 0, stream>>>(ei + EE, bhist, EE);
    bscan_kernel<<<1, 1024, 0, stream>>>(bhist, boffs, bcursor);
    bscatter_kernel<<<(EE + 255) / 256, 256, 0, stream>>>(ei, bcursor, epack, EE);
    bounds_kernel<<<(NN + 255) / 256, 256, 0, stream>>>(batch, gstart, NN);
    cast_kernel<<<(NN * DD / 4 + 255) / 256, 256, 0, stream>>>(x, xb);

    int aggB_grid = (NBUCK + 3) / 4;   // 4 waves (buckets) per block
    int mlp_grid = (NN + 255) / 256;

    // layer 0
    aggB_kernel<<<aggB_grid, 256, 0, stream>>>(xb, bufU, boffs, epack);
    mlp_kernel<true, true><<<mlp_grid, 256, 0, stream>>>(bufU, hA, w0a, b0a, w0b, b0b,
                                                         bn0g, bn0b, bn0m, bn0v, NN);
    // layer 1
    aggB_kernel<<<aggB_grid, 256, 0, stream>>>(hA, bufU, boffs, epack);
    mlp_kernel<true, true><<<mlp_grid, 256, 0, stream>>>(bufU, hB, w1a, b1a, w1b, b1b,
                                                         bn1g, bn1b, bn1m, bn1v, NN);
    // layer 2 (fp32 out, in-place on bufU: each thread reads its row before writing)
    aggB_kernel<<<aggB_grid, 256, 0, stream>>>(hB, bufU, boffs, epack);
    mlp_kernel<false, false><<<mlp_grid, 256, 0, stream>>>(bufU, bufU, w2a, b2a, w2b, b2b,
                                                           nullptr, nullptr, nullptr, nullptr, NN);

    // pooling (fp32 in, no atomics) + head
    pool_kernel<<<GG, 256, 0, stream>>>(bufU, gstart, pmean, pmax);
    head_kernel<<<GG, 64, 0, stream>>>(pmean, pmax, wp1, bp1, wp2, bp2, out);
}

// Round 8
// 487.348 us; speedup vs baseline: 3.5814x; 3.5814x over previous
//
#include <hip/hip_runtime.h>
#include <hip/hip_bf16.h>

#define NN 100000
#define EE 1250000
#define DD 64
#define GG 256
#define BN_NODES 16
#define NBUCK (NN / BN_NODES)   // 6250 (exact)

static __device__ __forceinline__ float relu_f(float x) { return fmaxf(x, 0.0f); }

static __device__ __forceinline__ float b2f(ushort u) {
    return __uint_as_float(((unsigned int)u) << 16);
}
static __device__ __forceinline__ ushort f2b(float f) {
    __hip_bfloat16 h = __float2bfloat16(f);  // RNE
    return *(ushort*)&h;
}

// ---------------- stage 1: coarse bucket sort of edges by dst>>4 ----------------

__global__ void bhist_kernel(const int* __restrict__ dst, int* __restrict__ bhist, int E) {
    int e = blockIdx.x * blockDim.x + threadIdx.x;
    if (e < E) atomicAdd(&bhist[dst[e] >> 4], 1);
}

// single-block exclusive scan over NBUCK=6250 (7 chunks of 1024)
__global__ __launch_bounds__(1024) void bscan_kernel(
    const int* __restrict__ bhist, int* __restrict__ boffs, int* __restrict__ bcursor) {
    __shared__ int tmp[1024];
    __shared__ int carry;
    int t = threadIdx.x;
    if (t == 0) carry = 0;
    __syncthreads();
    for (int base = 0; base < NBUCK; base += 1024) {
        int v = (base + t < NBUCK) ? bhist[base + t] : 0;
        tmp[t] = v;
        __syncthreads();
        for (int d = 1; d < 1024; d <<= 1) {
            int u = (t >= d) ? tmp[t - d] : 0;
            __syncthreads();
            tmp[t] += u;
            __syncthreads();
        }
        int excl = tmp[t] - v + carry;
        if (base + t < NBUCK) { boffs[base + t] = excl; bcursor[base + t] = excl; }
        __syncthreads();
        if (t == 1023) carry += tmp[1023];
        __syncthreads();
    }
    if (t == 0) boffs[NBUCK] = carry;
}

// pack src (20 bits) | dstLocal (4 bits) << 20; writes land in per-bucket windows
__global__ void bscatter_kernel(const int* __restrict__ ei, int* __restrict__ bcursor,
                                int* __restrict__ epack, int E) {
    int e = blockIdx.x * blockDim.x + threadIdx.x;
    if (e < E) {
        int s = ei[e];          // src
        int d = ei[E + e];      // dst
        int pos = atomicAdd(&bcursor[d >> 4], 1);
        epack[pos] = s | ((d & (BN_NODES - 1)) << 20);
    }
}

// ---------------- stage 2: refine buckets into exact CSR (contiguous writes) ----
__global__ __launch_bounds__(256) void refine_kernel(
    const int* __restrict__ epack, const int* __restrict__ boffs,
    int* __restrict__ srcs, int* __restrict__ off) {
    __shared__ int cnt[4][BN_NODES];
    __shared__ int pre[4][BN_NODES];
    int wave = threadIdx.x >> 6, lane = threadIdx.x & 63;
    int b = blockIdx.x * 4 + wave;
    bool active = (b < NBUCK);
    int j0 = 0, j1 = 0;
    if (active) { j0 = boffs[b]; j1 = boffs[b + 1]; }
    if (lane < BN_NODES) cnt[wave][lane] = 0;
    __syncthreads();
    if (active) {
        for (int j = j0 + lane; j < j1; j += 64)
            atomicAdd(&cnt[wave][epack[j] >> 20], 1);   // int LDS atomic, 1 lane-op/edge
    }
    __syncthreads();
    if (active && lane == 0) {
        int run = 0;
        for (int r = 0; r < BN_NODES; r++) { pre[wave][r] = run; run += cnt[wave][r]; }
    }
    __syncthreads();
    if (active && lane < BN_NODES) {
        off[b * BN_NODES + lane] = j0 + pre[wave][lane];
        cnt[wave][lane] = pre[wave][lane];              // reuse as cursor
        if (b == NBUCK - 1 && lane == 0) off[NN] = j1;
    }
    __syncthreads();
    if (active) {
        for (int j = j0 + lane; j < j1; j += 64) {
            int p = epack[j];
            int pos = j0 + atomicAdd(&cnt[wave][p >> 20], 1);
            srcs[pos] = p & 0xFFFFF;                    // contiguous per-bucket writes
        }
    }
}

// graph boundaries from sorted batch
__global__ void bounds_kernel(const int* __restrict__ batch, int* __restrict__ gstart, int n) {
    int i = blockIdx.x * blockDim.x + threadIdx.x;
    if (i >= n) return;
    int b = batch[i];
    int prev = (i == 0) ? -1 : batch[i - 1];
    for (int g = prev + 1; g <= b; g++) gstart[g] = i;
    if (i == n - 1) {
        for (int g = b + 1; g <= GG; g++) gstart[g] = n;
    }
}

// fp32 -> bf16 cast of x (once)
__global__ __launch_bounds__(256) void cast_kernel(const float* __restrict__ x,
                                                   ushort* __restrict__ xb) {
    size_t i = ((size_t)blockIdx.x * blockDim.x + threadIdx.x) * 4;
    if (i >= (size_t)NN * DD) return;
    float4 v = *(const float4*)(x + i);
    ushort4 r;
    r.x = f2b(v.x); r.y = f2b(v.y); r.z = f2b(v.z); r.w = f2b(v.w);
    *(ushort4*)(xb + i) = r;
}

// ---------------- aggregation: wave per node, bf16 gather, 8-deep unroll ------
__global__ __launch_bounds__(256) void agg_kernel(
    const ushort* __restrict__ xb, float* __restrict__ u,
    const int* __restrict__ off, const int* __restrict__ srcs, int n) {
    int node = blockIdx.x * 4 + (threadIdx.x >> 6);
    int lane = threadIdx.x & 63;
    if (node >= n) return;
    int o = off[node];
    int oe = off[node + 1];
    float a0 = b2f(xb[(size_t)node * DD + lane]);   // self
    float a1 = 0.0f, a2 = 0.0f, a3 = 0.0f, a4 = 0.0f, a5 = 0.0f, a6 = 0.0f, a7 = 0.0f;
    int j = o;
    for (; j + 8 <= oe; j += 8) {
        int s0 = srcs[j + 0], s1 = srcs[j + 1], s2 = srcs[j + 2], s3 = srcs[j + 3];
        int s4 = srcs[j + 4], s5 = srcs[j + 5], s6 = srcs[j + 6], s7 = srcs[j + 7];
        ushort v0 = xb[(size_t)s0 * DD + lane];
        ushort v1 = xb[(size_t)s1 * DD + lane];
        ushort v2 = xb[(size_t)s2 * DD + lane];
        ushort v3 = xb[(size_t)s3 * DD + lane];
        ushort v4 = xb[(size_t)s4 * DD + lane];
        ushort v5 = xb[(size_t)s5 * DD + lane];
        ushort v6 = xb[(size_t)s6 * DD + lane];
        ushort v7 = xb[(size_t)s7 * DD + lane];
        a0 += b2f(v0); a1 += b2f(v1); a2 += b2f(v2); a3 += b2f(v3);
        a4 += b2f(v4); a5 += b2f(v5); a6 += b2f(v6); a7 += b2f(v7);
    }
    for (; j + 4 <= oe; j += 4) {
        int s0 = srcs[j + 0], s1 = srcs[j + 1], s2 = srcs[j + 2], s3 = srcs[j + 3];
        ushort v0 = xb[(size_t)s0 * DD + lane];
        ushort v1 = xb[(size_t)s1 * DD + lane];
        ushort v2 = xb[(size_t)s2 * DD + lane];
        ushort v3 = xb[(size_t)s3 * DD + lane];
        a0 += b2f(v0); a1 += b2f(v1); a2 += b2f(v2); a3 += b2f(v3);
    }
    for (; j < oe; j++) a0 += b2f(xb[(size_t)srcs[j] * DD + lane]);
    u[(size_t)node * DD + lane] = ((a0 + a1) + (a2 + a3)) + ((a4 + a5) + (a6 + a7));
}

// ---------------- per-layer: fused MLP + outer ReLU (+ BN) -----------------
template <bool HAS_BN, bool OUT_BF16>
__global__ __launch_bounds__(256) void mlp_kernel(
    const float* __restrict__ u, void* __restrict__ hout,
    const float* __restrict__ wa, const float* __restrict__ ba,
    const float* __restrict__ wb, const float* __restrict__ bb,
    const float* __restrict__ bng, const float* __restrict__ bnb,
    const float* __restrict__ bnm, const float* __restrict__ bnv, int n) {
    int i = blockIdx.x * blockDim.x + threadIdx.x;
    if (i >= n) return;

    float uu[DD];
    const float4* up = (const float4*)(u + (size_t)i * DD);
#pragma unroll
    for (int q = 0; q < DD / 4; q++) {
        float4 v = up[q];
        uu[4 * q + 0] = v.x; uu[4 * q + 1] = v.y;
        uu[4 * q + 2] = v.z; uu[4 * q + 3] = v.w;
    }

    float acc[DD];
#pragma unroll
    for (int o = 0; o < DD; o++) acc[o] = bb[o];

#pragma unroll 1
    for (int j = 0; j < DD; j++) {   // j wave-uniform -> weight loads go scalar
        float a = ba[j];
#pragma unroll
        for (int k = 0; k < DD; k++) a = fmaf(uu[k], wa[k * DD + j], a);
        a = relu_f(a);
#pragma unroll
        for (int o = 0; o < DD; o++) acc[o] = fmaf(a, wb[j * DD + o], acc[o]);
    }

#pragma unroll
    for (int q = 0; q < DD / 4; q++) {
        float v[4];
#pragma unroll
        for (int c = 0; c < 4; c++) {
            int o = 4 * q + c;
            float t = relu_f(acc[o]);
            if (HAS_BN) {
                float sc = bng[o] * rsqrtf(bnv[o] + 1e-5f);
                float sh = bnb[o] - bnm[o] * sc;
                t = fmaf(t, sc, sh);
            }
            v[c] = t;
        }
        if (OUT_BF16) {
            ushort4 r;
            r.x = f2b(v[0]); r.y = f2b(v[1]); r.z = f2b(v[2]); r.w = f2b(v[3]);
            ((ushort4*)((ushort*)hout + (size_t)i * DD))[q] = r;
        } else {
            float4 r; r.x = v[0]; r.y = v[1]; r.z = v[2]; r.w = v[3];
            ((float4*)((float*)hout + (size_t)i * DD))[q] = r;
        }
    }
}

// ---------------- pooling: one block per graph, zero atomics ----------------
__global__ __launch_bounds__(256) void pool_kernel(
    const float* __restrict__ h, const int* __restrict__ gstart,
    float* __restrict__ pmean, float* __restrict__ pmax) {
    __shared__ float ssum[4][DD];
    __shared__ float smax[4][DD];
    int g = blockIdx.x;
    int lane = threadIdx.x & 63;
    int wave = threadIdx.x >> 6;
    int s = gstart[g], e = gstart[g + 1];
    float sum = 0.0f, mx = 0.0f;  // layer-2 out is post-ReLU >= 0; 0 == empty-graph guard
    for (int i = s + wave; i < e; i += 4) {
        float v = h[(size_t)i * DD + lane];
        sum += v;
        mx = fmaxf(mx, v);
    }
    ssum[wave][lane] = sum;
    smax[wave][lane] = mx;
    __syncthreads();
    if (wave == 0) {
        sum = ssum[0][lane] + ssum[1][lane] + ssum[2][lane] + ssum[3][lane];
        mx = fmaxf(fmaxf(smax[0][lane], smax[1][lane]),
                   fmaxf(smax[2][lane], smax[3][lane]));
        float cnt = fmaxf((float)(e - s), 1.0f);
        pmean[g * DD + lane] = sum / cnt;
        pmax[g * DD + lane] = mx;
    }
}

// ---------------- head: MLP + log_softmax, one 64-thread block per graph ----
__global__ __launch_bounds__(64) void head_kernel(
    const float* __restrict__ pmean, const float* __restrict__ pmax,
    const float* __restrict__ wp1, const float* __restrict__ bp1,
    const float* __restrict__ wp2, const float* __restrict__ bp2,
    float* __restrict__ out) {
    __shared__ float gx[2 * DD];
    int g = blockIdx.x;
    int lane = threadIdx.x;
    gx[lane] = pmean[g * DD + lane];
    gx[DD + lane] = pmax[g * DD + lane];
    __syncthreads();
    float t = bp1[lane];
    for (int k = 0; k < 2 * DD; k++) t = fmaf(gx[k], wp1[k * DD + lane], t);
    float p0 = t * wp2[lane * 2 + 0];
    float p1 = t * wp2[lane * 2 + 1];
    for (int o = 32; o > 0; o >>= 1) {
        p0 += __shfl_down(p0, o);
        p1 += __shfl_down(p1, o);
    }
    if (lane == 0) {
        p0 += bp2[0];
        p1 += bp2[1];
        float m = fmaxf(p0, p1);
        float lse = m + logf(expf(p0 - m) + expf(p1 - m));
        out[g * 2 + 0] = p0 - lse;
        out[g * 2 + 1] = p1 - lse;
    }
}

// ---------------- launch ----------------
extern "C" void kernel_launch(void* const* d_in, const int* in_sizes, int n_in,
                              void* d_out, int out_size, void* d_ws, size_t ws_size,
                              hipStream_t stream) {
    const float* x     = (const float*)d_in[0];
    const int*   ei    = (const int*)d_in[1];
    const int*   batch = (const int*)d_in[2];
    const float* w0a = (const float*)d_in[3];  const float* b0a = (const float*)d_in[4];
    const float* w0b = (const float*)d_in[5];  const float* b0b = (const float*)d_in[6];
    const float* w1a = (const float*)d_in[7];  const float* b1a = (const float*)d_in[8];
    const float* w1b = (const float*)d_in[9];  const float* b1b = (const float*)d_in[10];
    const float* w2a = (const float*)d_in[11]; const float* b2a = (const float*)d_in[12];
    const float* w2b = (const float*)d_in[13]; const float* b2b = (const float*)d_in[14];
    const float* bn0g = (const float*)d_in[15]; const float* bn0b = (const float*)d_in[16];
    const float* bn0m = (const float*)d_in[17]; const float* bn0v = (const float*)d_in[18];
    const float* bn1g = (const float*)d_in[19]; const float* bn1b = (const float*)d_in[20];
    const float* bn1m = (const float*)d_in[21]; const float* bn1v = (const float*)d_in[22];
    const float* wp1 = (const float*)d_in[23]; const float* bp1 = (const float*)d_in[24];
    const float* wp2 = (const float*)d_in[25]; const float* bp2 = (const float*)d_in[26];
    float* out = (float*)d_out;

    char* p = (char*)d_ws;
    auto take = [&](size_t bytes) {
        char* r = p;
        p += (bytes + 255) & ~(size_t)255;
        return r;
    };
    int* bhist   = (int*)take(NBUCK * sizeof(int));
    int* boffs   = (int*)take((NBUCK + 1) * sizeof(int));
    int* bcursor = (int*)take(NBUCK * sizeof(int));
    int* epack   = (int*)take(EE * sizeof(int));
    int* srcs    = (int*)take(EE * sizeof(int));
    int* off     = (int*)take((NN + 1) * sizeof(int));
    int* gstart  = (int*)take((GG + 1) * sizeof(int));
    ushort* xb   = (ushort*)take((size_t)NN * DD * sizeof(ushort));
    float* bufU  = (float*)take((size_t)NN * DD * sizeof(float));
    ushort* hA   = (ushort*)take((size_t)NN * DD * sizeof(ushort));
    ushort* hB   = (ushort*)take((size_t)NN * DD * sizeof(ushort));
    float* pmean = (float*)take(GG * DD * sizeof(float));
    float* pmax  = (float*)take(GG * DD * sizeof(float));

    // two-stage CSR build + graph bounds + x cast
    hipMemsetAsync(bhist, 0, NBUCK * sizeof(int), stream);
    bhist_kernel<<<(EE + 255) / 256, 256, 0, stream>>>(ei + EE, bhist, EE);
    bscan_kernel<<<1, 1024, 0, stream>>>(bhist, boffs, bcursor);
    bscatter_kernel<<<(EE + 255) / 256, 256, 0, stream>>>(ei, bcursor, epack, EE);
    refine_kernel<<<(NBUCK + 3) / 4, 256, 0, stream>>>(epack, boffs, srcs, off);
    bounds_kernel<<<(NN + 255) / 256, 256, 0, stream>>>(batch, gstart, NN);
    cast_kernel<<<(NN * DD / 4 + 255) / 256, 256, 0, stream>>>(x, xb);

    int agg_grid = (NN + 3) / 4;
    int mlp_grid = (NN + 255) / 256;

    // layer 0
    agg_kernel<<<agg_grid, 256, 0, stream>>>(xb, bufU, off, srcs, NN);
    mlp_kernel<true, true><<<mlp_grid, 256, 0, stream>>>(bufU, hA, w0a, b0a, w0b, b0b,
                                                         bn0g, bn0b, bn0m, bn0v, NN);
    // layer 1
    agg_kernel<<<agg_grid, 256, 0, stream>>>(hA, bufU, off, srcs, NN);
    mlp_kernel<true, true><<<mlp_grid, 256, 0, stream>>>(bufU, hB, w1a, b1a, w1b, b1b,
                                                         bn1g, bn1b, bn1m, bn1v, NN);
    // layer 2 (fp32 out, in-place on bufU: each thread reads its row before writing)
    agg_kernel<<<agg_grid, 256, 0, stream>>>(hB, bufU, off, srcs, NN);
    mlp_kernel<false, false><<<mlp_grid, 256, 0, stream>>>(bufU, bufU, w2a, b2a, w2b, b2b,
                                                           nullptr, nullptr, nullptr, nullptr, NN);

    // pooling (fp32 in, no atomics) + head
    pool_kernel<<<GG, 256, 0, stream>>>(bufU, gstart, pmean, pmax);
    head_kernel<<<GG, 64, 0, stream>>>(pmean, pmax, wp1, bp1, wp2, bp2, out);
}